// Round 5
// baseline (553.467 us; speedup 1.0000x reference)
//
#include <hip/hip_runtime.h>
#include <hip/hip_bf16.h>
#include <hip/hip_fp16.h>
#include <math.h>

#define NEG_SLOPE 0.2f

typedef unsigned int uint;
typedef __bf16 bf16x8 __attribute__((ext_vector_type(8)));
typedef __bf16 bf16x4 __attribute__((ext_vector_type(4)));
typedef __bf16 bf16x2 __attribute__((ext_vector_type(2)));
typedef _Float16 f16x2 __attribute__((ext_vector_type(2)));
typedef float floatx4 __attribute__((ext_vector_type(4)));

// Atomic counters padded to one 128B cache line per node (CPAD).
#define CPAD 5   // <<5 ints = 128 B

__device__ inline float2 h2_to_f2(uint v) {
    f16x2 p = __builtin_bit_cast(f16x2, v);
    return make_float2((float)p[0], (float)p[1]);
}

// ============================ CSR build =================================

// Single atomic pass: count degrees AND record each edge's rank within its
// dst segment (rank = atomicAdd old value). int4 loads, 4 independent
// atomic chains, sequential int4 rank store.
__global__ void count_deg_rank(const int* __restrict__ dst, int* __restrict__ deg,
                               int* __restrict__ rank, int E) {
    int t = blockIdx.x * blockDim.x + threadIdx.x;
    int stride = gridDim.x * blockDim.x;
    int E4 = E >> 2;
    for (int i4 = t; i4 < E4; i4 += stride) {
        int4 d4 = ((const int4*)dst)[i4];
        int4 r4;
        r4.x = atomicAdd(&deg[d4.x << CPAD], 1);
        r4.y = atomicAdd(&deg[d4.y << CPAD], 1);
        r4.z = atomicAdd(&deg[d4.z << CPAD], 1);
        r4.w = atomicAdd(&deg[d4.w << CPAD], 1);
        ((int4*)rank)[i4] = r4;
    }
    for (int i = (E4 << 2) + t; i < E; i += stride)
        rank[i] = atomicAdd(&deg[dst[i] << CPAD], 1);
}

__global__ void scan_block_k(const int* __restrict__ deg, int* __restrict__ off,
                             int* __restrict__ bsum, int N) {
    __shared__ int sdata[256];
    int t = threadIdx.x;
    int base = blockIdx.x * 1024 + t * 4;
    int v0 = (base + 0 < N) ? deg[(base + 0) << CPAD] : 0;
    int v1 = (base + 1 < N) ? deg[(base + 1) << CPAD] : 0;
    int v2 = (base + 2 < N) ? deg[(base + 2) << CPAD] : 0;
    int v3 = (base + 3 < N) ? deg[(base + 3) << CPAD] : 0;
    int s = v0 + v1 + v2 + v3;
    sdata[t] = s;
    __syncthreads();
    for (int d = 1; d < 256; d <<= 1) {
        int x = (t >= d) ? sdata[t - d] : 0;
        __syncthreads();
        sdata[t] += x;
        __syncthreads();
    }
    int run = sdata[t] - s;  // exclusive prefix within block
    if (t == 255) bsum[blockIdx.x] = sdata[255];
    if (base + 0 < N) off[base + 0] = run; run += v0;
    if (base + 1 < N) off[base + 1] = run; run += v1;
    if (base + 2 < N) off[base + 2] = run; run += v2;
    if (base + 3 < N) off[base + 3] = run;
}

__global__ void scan_bsum_k(int* bsum, int G) {
    __shared__ int sdata[1024];
    int t = threadIdx.x;
    int v = (t < G) ? bsum[t] : 0;
    sdata[t] = v;
    __syncthreads();
    for (int d = 1; d < 1024; d <<= 1) {
        int x = (t >= d) ? sdata[t - d] : 0;
        __syncthreads();
        sdata[t] += x;
        __syncthreads();
    }
    if (t < G) bsum[t] = sdata[t] - v;  // exclusive
}

__global__ void add_bsum_k(int* __restrict__ off, const int* __restrict__ bsum,
                           int N, int Etot) {
    int i = blockIdx.x * blockDim.x + threadIdx.x;
    if (i < N) off[i] += bsum[i >> 10];
    else if (i == N) off[N] = Etot;
}

// Atomic-free streaming scatter into the .y (src) field of the {w,src}
// pair records: p = off[dst] + rank. Edge list read once, stores
// fire-and-forget.
__global__ void fill_scatter(const int* __restrict__ src, const int* __restrict__ dst,
                             const int* __restrict__ rank, const int* __restrict__ off,
                             int* __restrict__ pair_raw, int E) {
    int t = blockIdx.x * blockDim.x + threadIdx.x;
    int stride = gridDim.x * blockDim.x;
    int E4 = E >> 2;
    for (int i4 = t; i4 < E4; i4 += stride) {
        int4 d4 = ((const int4*)dst)[i4];
        int4 s4 = ((const int4*)src)[i4];
        int4 r4 = ((const int4*)rank)[i4];
        pair_raw[((off[d4.x] + r4.x) << 1) + 1] = s4.x;
        pair_raw[((off[d4.y] + r4.y) << 1) + 1] = s4.y;
        pair_raw[((off[d4.z] + r4.z) << 1) + 1] = s4.z;
        pair_raw[((off[d4.w] + r4.w) << 1) + 1] = s4.w;
    }
    for (int i = (E4 << 2) + t; i < E; i += stride)
        pair_raw[((off[dst[i]] + rank[i]) << 1) + 1] = src[i];
}

// ===================== splits (fp32 -> hi/lo bf16) =======================

__global__ void split_x_k(const float* __restrict__ in, __bf16* __restrict__ hi,
                          __bf16* __restrict__ lo, int n4) {
    int i = blockIdx.x * blockDim.x + threadIdx.x;
    if (i >= n4) return;
    float4 v = ((const float4*)in)[i];
    bf16x4 h = { (__bf16)v.x, (__bf16)v.y, (__bf16)v.z, (__bf16)v.w };
    bf16x4 l = { (__bf16)(v.x - (float)h[0]), (__bf16)(v.y - (float)h[1]),
                 (__bf16)(v.z - (float)h[2]), (__bf16)(v.w - (float)h[3]) };
    ((bf16x4*)hi)[i] = h;
    ((bf16x4*)lo)[i] = l;
}

// split + fragment-order all three 128x128 W's.
// Wf element (ct,kt,q,n16,j) holds W[k][ncol] with k = kt*32+q*8+j,
// ncol = ct*16+n16. Flat: (((ct*4+kt)*64) + q*16 + n16)*8 + j
// -> a wave's B-frag load (fixed ct,kt; lane = q*16+n16) is contiguous 1 KB.
__global__ void split_w_k(const float* __restrict__ W0, const float* __restrict__ W1,
                          const float* __restrict__ W2, __bf16* __restrict__ Wfh,
                          __bf16* __restrict__ Wfl) {
    const float* W = (blockIdx.y == 0) ? W0 : (blockIdx.y == 1) ? W1 : W2;
    size_t base = (size_t)blockIdx.y * 16384;
    int i = blockIdx.x * 256 + threadIdx.x;   // 0..16383
    int k = i >> 7, ncol = i & 127;
    int ct = ncol >> 4, n16 = ncol & 15;
    int kt = k >> 5, q = (k & 31) >> 3, j = k & 7;
    size_t flat = (size_t)(((ct * 4 + kt) * 64) + q * 16 + n16) * 8 + j;
    float v = W[i];
    __bf16 h = (__bf16)v;
    __bf16 l = (__bf16)(v - (float)h);
    Wfh[base + flat] = h;
    Wfl[base + flat] = l;
}

// ================ split-bf16 MFMA GEMM + fused alphas ====================
// h = Ah*Wh + Ah*Wl + Al*Wh  (fp32-equivalent, rel err ~2^-18).
// 256 threads = 4 waves; wave = 16-row strip x 128 cols,
// 8 col-tiles x 4 k-steps x 3 MFMAs. W fragments staged once per block into
// 64KB LDS; frag reads are ds_read_b128, stride-16B = conflict free. LDS
// buffer aliased with the fp16-H epilogue staging.

__global__ __launch_bounds__(256, 2) void gemm_split(
    const __bf16* __restrict__ Ah, const __bf16* __restrict__ Al,
    const __bf16* __restrict__ Wh, const __bf16* __restrict__ Wl,
    const float* __restrict__ avs, const float* __restrict__ avd,
    _Float16* __restrict__ Hh, float* __restrict__ asrc, float* __restrict__ adst,
    int M) {
    __shared__ __align__(16) char lds_raw[65536];   // W stage; aliased as hl later
    int tid = threadIdx.x;
    int wv = tid >> 6, lane = tid & 63;
    int n = lane & 15, q = lane >> 4;

    // ---- stage Wh (32KB) -> lds[0:32768), Wl (32KB) -> lds[32768:65536)
    #pragma unroll
    for (int it = 0; it < 16; ++it) {
        int boff = it * 4096 + tid * 16;            // 4KB per iteration
        const char* s = (it < 8) ? ((const char*)Wh + boff)
                                 : ((const char*)Wl + (boff - 32768));
        *(float4*)(lds_raw + boff) = *(const float4*)s;
    }

    int arow_g = blockIdx.x * 64 + wv * 16 + n;
    int arow_c = (arow_g < M) ? arow_g : (M - 1);
    const bf16x8* ah = (const bf16x8*)(Ah + (size_t)arow_c * 128);
    const bf16x8* al = (const bf16x8*)(Al + (size_t)arow_c * 128);
    bf16x8 a_h[4], a_l[4];
    #pragma unroll
    for (int kt = 0; kt < 4; ++kt) {
        a_h[kt] = ah[kt * 4 + q];   // k = kt*32 + q*8 + j
        a_l[kt] = al[kt * 4 + q];
    }
    __syncthreads();   // W staged

    floatx4 acc[8];
    #pragma unroll
    for (int ct = 0; ct < 8; ++ct) {
        floatx4 c = {0.f, 0.f, 0.f, 0.f};
        #pragma unroll
        for (int kt = 0; kt < 4; ++kt) {
            int fo = ((ct * 4 + kt) * 64 + lane) * 16;   // byte offset, <32768
            bf16x8 bh = *(const bf16x8*)(lds_raw + fo);
            bf16x8 bl = *(const bf16x8*)(lds_raw + 32768 + fo);
            c = __builtin_amdgcn_mfma_f32_16x16x32_bf16(a_h[kt], bh, c, 0, 0, 0);
            c = __builtin_amdgcn_mfma_f32_16x16x32_bf16(a_h[kt], bl, c, 0, 0, 0);
            c = __builtin_amdgcn_mfma_f32_16x16x32_bf16(a_l[kt], bh, c, 0, 0, 0);
        }
        acc[ct] = c;
    }

    // fused alphas. D layout: row = q*4+r, col = ct*16+n.
    float ps[4] = {0.f, 0.f, 0.f, 0.f}, pd[4] = {0.f, 0.f, 0.f, 0.f};
    #pragma unroll
    for (int ct = 0; ct < 8; ++ct) {
        float sv = avs[ct * 16 + n], dv = avd[ct * 16 + n];
        #pragma unroll
        for (int r = 0; r < 4; ++r) {
            ps[r] += acc[ct][r] * sv;
            pd[r] += acc[ct][r] * dv;
        }
    }
    #pragma unroll
    for (int m = 1; m < 16; m <<= 1) {
        #pragma unroll
        for (int r = 0; r < 4; ++r) {
            ps[r] += __shfl_xor(ps[r], m, 64);
            pd[r] += __shfl_xor(pd[r], m, 64);
        }
    }
    if (n == 0) {
        #pragma unroll
        for (int r = 0; r < 4; ++r) {
            int grow = blockIdx.x * 64 + wv * 16 + q * 4 + r;
            if (grow < M) { asrc[grow] = ps[r]; adst[grow] = pd[r]; }
        }
    }

    // fp16 H store via LDS (coalesced uint). lds_raw aliased -> barrier first.
    __syncthreads();
    _Float16 (*hl)[132] = (_Float16(*)[132])lds_raw;
    #pragma unroll
    for (int ct = 0; ct < 8; ++ct)
        #pragma unroll
        for (int r = 0; r < 4; ++r)
            hl[wv * 16 + q * 4 + r][ct * 16 + n] = (_Float16)acc[ct][r];
    __syncthreads();

    int r0 = blockIdx.x * 64;
    for (int i = tid; i < 64 * 64; i += 256) {
        int rr = i >> 6, cu = i & 63;
        int gr = r0 + rr;
        if (gr < M)
            ((uint*)Hh)[(size_t)gr * 64 + cu] = *(const uint*)&hl[rr][cu * 2];
    }
}

// ===================== per-edge softmax weights ==========================
// 4 nodes per wave (16 lanes each). Reads the pair record's src field,
// computes w = exp(lrelu(asrc[s]+adst[d])), rewrites the full 8B pair
// {w, s} (16 consecutive pairs per lane-group = 128B merged stores).
// Same arithmetic as reference; same weight values bit-for-bit.

__global__ __launch_bounds__(256) void edge_w_k(
    const float* __restrict__ asrc, const float* __restrict__ adst,
    const int* __restrict__ off, int2* __restrict__ ewp,
    float* __restrict__ wself, int N) {
    int gid = blockIdx.x * blockDim.x + threadIdx.x;
    int wave = gid >> 6, lane = gid & 63;
    int node = wave * 4 + (lane >> 4);
    int l16 = lane & 15;
    if (node >= N) return;
    float ad = adst[node];
    int beg = off[node], end = off[node + 1];
    if (l16 == 0) {
        float e = asrc[node] + ad;
        e = (e > 0.f) ? e : NEG_SLOPE * e;
        wself[node] = __expf(e);
    }
    for (int p = beg + l16; p < end; p += 16) {
        int s = ewp[p].y;
        float e = asrc[s] + ad;
        e = (e > 0.f) ? e : NEG_SLOPE * e;
        ewp[p] = make_int2(__float_as_int(__expf(e)), s);
    }
}

// ========================= edge aggregation ==============================
// one wave per dst node; fp16 h rows (256 B, one uint/lane). Edges in
// masked chunks of 4. Round-5: {weight,src} fused into one int2 record
// (one 8B load/edge replaces separate csr+ew loads) and a 1-deep software
// pipeline: chunk j+4's records are prefetched while chunk j's row gathers
// (indices loaded LAST iteration) are in flight — breaks the per-iteration
// index->gather dependency that kept both pipes under 50%.
// Summation order identical to previous rounds -> bit-same output.

template <int FINAL>
__global__ __launch_bounds__(256) void aggregate_k(
    const _Float16* __restrict__ h, const int2* __restrict__ ewp,
    const float* __restrict__ wself, const int* __restrict__ off,
    const float* __restrict__ bias,
    float* __restrict__ out_f, __bf16* __restrict__ a_hi, __bf16* __restrict__ a_lo,
    int N, int E) {
    int gid = blockIdx.x * blockDim.x + threadIdx.x;
    int wid = gid >> 6, lane = gid & 63;
    if (wid >= N) return;
    const uint* hrows = (const uint*)h;   // 64 uints (128 fp16) per row
    float acc0, acc1, denom;

    {   // self loop
        float w = wself[wid];
        float2 f = h2_to_f2(hrows[(size_t)wid * 64 + lane]);
        denom = w; acc0 = w * f.x; acc1 = w * f.y;
    }

    int beg = __builtin_amdgcn_readfirstlane(off[wid]);
    int end = __builtin_amdgcn_readfirstlane(off[wid + 1]);
    int Em1 = E - 1;

    // preload first chunk's records (clamped)
    int2 q0 = ewp[(beg + 0 <= Em1) ? beg + 0 : Em1];
    int2 q1 = ewp[(beg + 1 <= Em1) ? beg + 1 : Em1];
    int2 q2 = ewp[(beg + 2 <= Em1) ? beg + 2 : Em1];
    int2 q3 = ewp[(beg + 3 <= Em1) ? beg + 3 : Em1];

    for (int j = beg; j < end; j += 4) {
        // prefetch next chunk's records (independent of this chunk's gathers)
        int jn = j + 4;
        int2 n0 = ewp[(jn + 0 <= Em1) ? jn + 0 : Em1];
        int2 n1 = ewp[(jn + 1 <= Em1) ? jn + 1 : Em1];
        int2 n2 = ewp[(jn + 2 <= Em1) ? jn + 2 : Em1];
        int2 n3 = ewp[(jn + 3 <= Em1) ? jn + 3 : Em1];

        // row gathers from records loaded last iteration: issue immediately
        int s0 = __builtin_amdgcn_readfirstlane(q0.y);
        int s1 = __builtin_amdgcn_readfirstlane(q1.y);
        int s2 = __builtin_amdgcn_readfirstlane(q2.y);
        int s3 = __builtin_amdgcn_readfirstlane(q3.y);
        uint v0 = hrows[(size_t)s0 * 64 + lane];
        uint v1 = hrows[(size_t)s1 * 64 + lane];
        uint v2 = hrows[(size_t)s2 * 64 + lane];
        uint v3 = hrows[(size_t)s3 * 64 + lane];

        float w0 = __int_as_float(q0.x);
        float w1 = (j + 1 < end) ? __int_as_float(q1.x) : 0.f;
        float w2 = (j + 2 < end) ? __int_as_float(q2.x) : 0.f;
        float w3 = (j + 3 < end) ? __int_as_float(q3.x) : 0.f;

        denom += (w0 + w1) + (w2 + w3);
        float2 f0 = h2_to_f2(v0), f1 = h2_to_f2(v1);
        float2 f2 = h2_to_f2(v2), f3 = h2_to_f2(v3);
        acc0 += w0 * f0.x + w1 * f1.x + w2 * f2.x + w3 * f3.x;
        acc1 += w0 * f0.y + w1 * f1.y + w2 * f2.y + w3 * f3.y;

        q0 = n0; q1 = n1; q2 = n2; q3 = n3;
    }

    float inv = 1.0f / denom;
    float2 b2 = ((const float2*)bias)[lane];
    float o0 = acc0 * inv + b2.x;
    float o1 = acc1 * inv + b2.y;
    if (FINAL) {
        ((float2*)out_f)[(size_t)wid * 64 + lane] = make_float2(o0, o1);
    } else {
        o0 = (o0 > 0.f) ? o0 : (__expf(o0) - 1.0f);   // ELU
        o1 = (o1 > 0.f) ? o1 : (__expf(o1) - 1.0f);
        __bf16 h0 = (__bf16)o0, h1 = (__bf16)o1;
        bf16x2 ph = { h0, h1 };
        bf16x2 pl = { (__bf16)(o0 - (float)h0), (__bf16)(o1 - (float)h1) };
        ((bf16x2*)a_hi)[(size_t)wid * 64 + lane] = ph;
        ((bf16x2*)a_lo)[(size_t)wid * 64 + lane] = pl;
    }
}

// ============================ launch =====================================

extern "C" void kernel_launch(void* const* d_in, const int* in_sizes, int n_in,
                              void* d_out, int out_size, void* d_ws, size_t ws_size,
                              hipStream_t stream) {
    const float* x = (const float*)d_in[0];
    const int* ei = (const int*)d_in[1];
    int N = in_sizes[0] / 128;
    int E = in_sizes[1] / 2;
    const int* src = ei;
    const int* dst = ei + E;

    const float* Wl_[3] = { (const float*)d_in[2], (const float*)d_in[6], (const float*)d_in[10] };
    const float* asl[3] = { (const float*)d_in[3], (const float*)d_in[7], (const float*)d_in[11] };
    const float* adl[3] = { (const float*)d_in[4], (const float*)d_in[8], (const float*)d_in[12] };
    const float* bl[3]  = { (const float*)d_in[5], (const float*)d_in[9], (const float*)d_in[13] };

    // ---- workspace (~40 MB) ----
    size_t nfeat = (size_t)N * 128;
    char* p = (char*)d_ws;
    _Float16* Hh = (_Float16*)p; p += nfeat * 2;       // fp16 gather table
    __bf16* Wfh = (__bf16*)p; p += 3 * 16384 * 2;      // fragment-ordered W hi
    __bf16* Wfl = (__bf16*)p; p += 3 * 16384 * 2;      // fragment-ordered W lo
    float* asrc = (float*)p;  p += (size_t)N * 4;
    float* adst = (float*)p;  p += (size_t)N * 4;
    int* off    = (int*)p;    p += (size_t)(N + 1) * 4;
    int* bsum   = (int*)p;    p += 4096 * 4;
    float* wself = (float*)p; p += (size_t)N * 4;      // self-loop weights
    int2* ewp   = (int2*)p;   p += (size_t)E * 8;      // {weight, src} records

    // Scratch that ALIASES the Hh region (dead until the first gemm, which
    // runs after CSR build): padded deg counters (N*128B = 12.8MB) then the
    // per-edge rank array (6.4MB). 19.2MB <= Hh's 25.6MB.
    int* cpad = (int*)Hh;
    int* rank = (int*)((char*)Hh + ((size_t)N << CPAD) * sizeof(int));

    // activations ping-pong through d_out: hi then lo bf16 (= 51.2 MB total)
    __bf16* A_hi = (__bf16*)d_out;
    __bf16* A_lo = A_hi + nfeat;

    int G = (N + 1023) / 1024;

    // ---- CSR build (grouped by dst) ----
    hipMemsetAsync(cpad, 0, ((size_t)N << CPAD) * sizeof(int), stream);
    count_deg_rank<<<2048, 256, 0, stream>>>(dst, cpad, rank, E);
    scan_block_k<<<G, 256, 0, stream>>>(cpad, off, bsum, N);
    scan_bsum_k<<<1, 1024, 0, stream>>>(bsum, G);
    add_bsum_k<<<(N + 256) / 256, 256, 0, stream>>>(off, bsum, N, E);
    fill_scatter<<<2048, 256, 0, stream>>>(src, dst, rank, off, (int*)ewp, E);

    // ---- splits ----
    split_w_k<<<dim3(64, 3), 256, 0, stream>>>(Wl_[0], Wl_[1], Wl_[2], Wfh, Wfl);
    int n4 = (int)(nfeat / 4);
    split_x_k<<<(n4 + 255) / 256, 256, 0, stream>>>(x, A_hi, A_lo, n4);

    int gemm_blocks = (N + 63) / 64;
    int wave_blocks = (N + 3) / 4;
    int ew_blocks = (N + 15) / 16;

    for (int l = 0; l < 3; ++l) {
        gemm_split<<<gemm_blocks, 256, 0, stream>>>(
            A_hi, A_lo, Wfh + (size_t)l * 16384, Wfl + (size_t)l * 16384,
            asl[l], adl[l], Hh, asrc, adst, N);
        edge_w_k<<<ew_blocks, 256, 0, stream>>>(asrc, adst, off, ewp, wself, N);
        if (l < 2) {
            aggregate_k<0><<<wave_blocks, 256, 0, stream>>>(
                Hh, ewp, wself, off, bl[l], nullptr, A_hi, A_lo, N, E);
        } else {
            aggregate_k<1><<<wave_blocks, 256, 0, stream>>>(
                Hh, ewp, wself, off, bl[l], (float*)d_out, nullptr, nullptr, N, E);
        }
    }
}

// Round 6
// 503.830 us; speedup vs baseline: 1.0985x; 1.0985x over previous
//
#include <hip/hip_runtime.h>
#include <hip/hip_bf16.h>
#include <hip/hip_fp16.h>
#include <math.h>

#define NEG_SLOPE 0.2f

typedef unsigned int uint;
typedef __bf16 bf16x8 __attribute__((ext_vector_type(8)));
typedef __bf16 bf16x4 __attribute__((ext_vector_type(4)));
typedef __bf16 bf16x2 __attribute__((ext_vector_type(2)));
typedef _Float16 f16x2 __attribute__((ext_vector_type(2)));
typedef float floatx4 __attribute__((ext_vector_type(4)));

// Atomic counters padded to one 128B cache line per node (CPAD).
#define CPAD 5   // <<5 ints = 128 B

__device__ inline float2 h2_to_f2(uint v) {
    f16x2 p = __builtin_bit_cast(f16x2, v);
    return make_float2((float)p[0], (float)p[1]);
}

// ============================ CSR build =================================

// Single atomic pass: count degrees AND record each edge's rank within its
// dst segment (rank = atomicAdd old value). int4 loads, 4 independent
// atomic chains, sequential int4 rank store.
__global__ void count_deg_rank(const int* __restrict__ dst, int* __restrict__ deg,
                               int* __restrict__ rank, int E) {
    int t = blockIdx.x * blockDim.x + threadIdx.x;
    int stride = gridDim.x * blockDim.x;
    int E4 = E >> 2;
    for (int i4 = t; i4 < E4; i4 += stride) {
        int4 d4 = ((const int4*)dst)[i4];
        int4 r4;
        r4.x = atomicAdd(&deg[d4.x << CPAD], 1);
        r4.y = atomicAdd(&deg[d4.y << CPAD], 1);
        r4.z = atomicAdd(&deg[d4.z << CPAD], 1);
        r4.w = atomicAdd(&deg[d4.w << CPAD], 1);
        ((int4*)rank)[i4] = r4;
    }
    for (int i = (E4 << 2) + t; i < E; i += stride)
        rank[i] = atomicAdd(&deg[dst[i] << CPAD], 1);
}

__global__ void scan_block_k(const int* __restrict__ deg, int* __restrict__ off,
                             int* __restrict__ bsum, int N) {
    __shared__ int sdata[256];
    int t = threadIdx.x;
    int base = blockIdx.x * 1024 + t * 4;
    int v0 = (base + 0 < N) ? deg[(base + 0) << CPAD] : 0;
    int v1 = (base + 1 < N) ? deg[(base + 1) << CPAD] : 0;
    int v2 = (base + 2 < N) ? deg[(base + 2) << CPAD] : 0;
    int v3 = (base + 3 < N) ? deg[(base + 3) << CPAD] : 0;
    int s = v0 + v1 + v2 + v3;
    sdata[t] = s;
    __syncthreads();
    for (int d = 1; d < 256; d <<= 1) {
        int x = (t >= d) ? sdata[t - d] : 0;
        __syncthreads();
        sdata[t] += x;
        __syncthreads();
    }
    int run = sdata[t] - s;  // exclusive prefix within block
    if (t == 255) bsum[blockIdx.x] = sdata[255];
    if (base + 0 < N) off[base + 0] = run; run += v0;
    if (base + 1 < N) off[base + 1] = run; run += v1;
    if (base + 2 < N) off[base + 2] = run; run += v2;
    if (base + 3 < N) off[base + 3] = run;
}

__global__ void scan_bsum_k(int* bsum, int G) {
    __shared__ int sdata[1024];
    int t = threadIdx.x;
    int v = (t < G) ? bsum[t] : 0;
    sdata[t] = v;
    __syncthreads();
    for (int d = 1; d < 1024; d <<= 1) {
        int x = (t >= d) ? sdata[t - d] : 0;
        __syncthreads();
        sdata[t] += x;
        __syncthreads();
    }
    if (t < G) bsum[t] = sdata[t] - v;  // exclusive
}

__global__ void add_bsum_k(int* __restrict__ off, const int* __restrict__ bsum,
                           int N, int Etot) {
    int i = blockIdx.x * blockDim.x + threadIdx.x;
    if (i < N) off[i] += bsum[i >> 10];
    else if (i == N) off[N] = Etot;
}

// Atomic-free streaming scatter: p = off[dst] + rank. Edge list read once,
// stores fire-and-forget (4B per edge).
__global__ void fill_scatter(const int* __restrict__ src, const int* __restrict__ dst,
                             const int* __restrict__ rank, const int* __restrict__ off,
                             int* __restrict__ csr_src, int E) {
    int t = blockIdx.x * blockDim.x + threadIdx.x;
    int stride = gridDim.x * blockDim.x;
    int E4 = E >> 2;
    for (int i4 = t; i4 < E4; i4 += stride) {
        int4 d4 = ((const int4*)dst)[i4];
        int4 s4 = ((const int4*)src)[i4];
        int4 r4 = ((const int4*)rank)[i4];
        csr_src[off[d4.x] + r4.x] = s4.x;
        csr_src[off[d4.y] + r4.y] = s4.y;
        csr_src[off[d4.z] + r4.z] = s4.z;
        csr_src[off[d4.w] + r4.w] = s4.w;
    }
    for (int i = (E4 << 2) + t; i < E; i += stride)
        csr_src[off[dst[i]] + rank[i]] = src[i];
}

// ===================== splits (fp32 -> hi/lo bf16) =======================

__global__ void split_x_k(const float* __restrict__ in, __bf16* __restrict__ hi,
                          __bf16* __restrict__ lo, int n4) {
    int i = blockIdx.x * blockDim.x + threadIdx.x;
    if (i >= n4) return;
    float4 v = ((const float4*)in)[i];
    bf16x4 h = { (__bf16)v.x, (__bf16)v.y, (__bf16)v.z, (__bf16)v.w };
    bf16x4 l = { (__bf16)(v.x - (float)h[0]), (__bf16)(v.y - (float)h[1]),
                 (__bf16)(v.z - (float)h[2]), (__bf16)(v.w - (float)h[3]) };
    ((bf16x4*)hi)[i] = h;
    ((bf16x4*)lo)[i] = l;
}

// split + fragment-order all three 128x128 W's.
// Wf element (ct,kt,q,n16,j) holds W[k][ncol] with k = kt*32+q*8+j,
// ncol = ct*16+n16. Flat: (((ct*4+kt)*64) + q*16 + n16)*8 + j
// -> a wave's B-frag load (fixed ct,kt; lane = q*16+n16) is contiguous 1 KB.
__global__ void split_w_k(const float* __restrict__ W0, const float* __restrict__ W1,
                          const float* __restrict__ W2, __bf16* __restrict__ Wfh,
                          __bf16* __restrict__ Wfl) {
    const float* W = (blockIdx.y == 0) ? W0 : (blockIdx.y == 1) ? W1 : W2;
    size_t base = (size_t)blockIdx.y * 16384;
    int i = blockIdx.x * 256 + threadIdx.x;   // 0..16383
    int k = i >> 7, ncol = i & 127;
    int ct = ncol >> 4, n16 = ncol & 15;
    int kt = k >> 5, q = (k & 31) >> 3, j = k & 7;
    size_t flat = (size_t)(((ct * 4 + kt) * 64) + q * 16 + n16) * 8 + j;
    float v = W[i];
    __bf16 h = (__bf16)v;
    __bf16 l = (__bf16)(v - (float)h);
    Wfh[base + flat] = h;
    Wfl[base + flat] = l;
}

// ================ split-bf16 MFMA GEMM + fused alphas ====================
// h = Ah*Wh + Ah*Wl + Al*Wh  (fp32-equivalent, rel err ~2^-18).
// 256 threads = 4 waves; wave = 16-row strip x 128 cols,
// 8 col-tiles x 4 k-steps x 3 MFMAs. W fragments staged once per block into
// 64KB LDS; frag reads are ds_read_b128, stride-16B = conflict free. LDS
// buffer aliased with the fp16-H epilogue staging.

__global__ __launch_bounds__(256, 2) void gemm_split(
    const __bf16* __restrict__ Ah, const __bf16* __restrict__ Al,
    const __bf16* __restrict__ Wh, const __bf16* __restrict__ Wl,
    const float* __restrict__ avs, const float* __restrict__ avd,
    _Float16* __restrict__ Hh, float* __restrict__ asrc, float* __restrict__ adst,
    int M) {
    __shared__ __align__(16) char lds_raw[65536];   // W stage; aliased as hl later
    int tid = threadIdx.x;
    int wv = tid >> 6, lane = tid & 63;
    int n = lane & 15, q = lane >> 4;

    // ---- stage Wh (32KB) -> lds[0:32768), Wl (32KB) -> lds[32768:65536)
    #pragma unroll
    for (int it = 0; it < 16; ++it) {
        int boff = it * 4096 + tid * 16;            // 4KB per iteration
        const char* s = (it < 8) ? ((const char*)Wh + boff)
                                 : ((const char*)Wl + (boff - 32768));
        *(float4*)(lds_raw + boff) = *(const float4*)s;
    }

    int arow_g = blockIdx.x * 64 + wv * 16 + n;
    int arow_c = (arow_g < M) ? arow_g : (M - 1);
    const bf16x8* ah = (const bf16x8*)(Ah + (size_t)arow_c * 128);
    const bf16x8* al = (const bf16x8*)(Al + (size_t)arow_c * 128);
    bf16x8 a_h[4], a_l[4];
    #pragma unroll
    for (int kt = 0; kt < 4; ++kt) {
        a_h[kt] = ah[kt * 4 + q];   // k = kt*32 + q*8 + j
        a_l[kt] = al[kt * 4 + q];
    }
    __syncthreads();   // W staged

    floatx4 acc[8];
    #pragma unroll
    for (int ct = 0; ct < 8; ++ct) {
        floatx4 c = {0.f, 0.f, 0.f, 0.f};
        #pragma unroll
        for (int kt = 0; kt < 4; ++kt) {
            int fo = ((ct * 4 + kt) * 64 + lane) * 16;   // byte offset, <32768
            bf16x8 bh = *(const bf16x8*)(lds_raw + fo);
            bf16x8 bl = *(const bf16x8*)(lds_raw + 32768 + fo);
            c = __builtin_amdgcn_mfma_f32_16x16x32_bf16(a_h[kt], bh, c, 0, 0, 0);
            c = __builtin_amdgcn_mfma_f32_16x16x32_bf16(a_h[kt], bl, c, 0, 0, 0);
            c = __builtin_amdgcn_mfma_f32_16x16x32_bf16(a_l[kt], bh, c, 0, 0, 0);
        }
        acc[ct] = c;
    }

    // fused alphas. D layout: row = q*4+r, col = ct*16+n.
    float ps[4] = {0.f, 0.f, 0.f, 0.f}, pd[4] = {0.f, 0.f, 0.f, 0.f};
    #pragma unroll
    for (int ct = 0; ct < 8; ++ct) {
        float sv = avs[ct * 16 + n], dv = avd[ct * 16 + n];
        #pragma unroll
        for (int r = 0; r < 4; ++r) {
            ps[r] += acc[ct][r] * sv;
            pd[r] += acc[ct][r] * dv;
        }
    }
    #pragma unroll
    for (int m = 1; m < 16; m <<= 1) {
        #pragma unroll
        for (int r = 0; r < 4; ++r) {
            ps[r] += __shfl_xor(ps[r], m, 64);
            pd[r] += __shfl_xor(pd[r], m, 64);
        }
    }
    if (n == 0) {
        #pragma unroll
        for (int r = 0; r < 4; ++r) {
            int grow = blockIdx.x * 64 + wv * 16 + q * 4 + r;
            if (grow < M) { asrc[grow] = ps[r]; adst[grow] = pd[r]; }
        }
    }

    // fp16 H store via LDS (coalesced uint). lds_raw aliased -> barrier first.
    __syncthreads();
    _Float16 (*hl)[132] = (_Float16(*)[132])lds_raw;
    #pragma unroll
    for (int ct = 0; ct < 8; ++ct)
        #pragma unroll
        for (int r = 0; r < 4; ++r)
            hl[wv * 16 + q * 4 + r][ct * 16 + n] = (_Float16)acc[ct][r];
    __syncthreads();

    int r0 = blockIdx.x * 64;
    for (int i = tid; i < 64 * 64; i += 256) {
        int rr = i >> 6, cu = i & 63;
        int gr = r0 + rr;
        if (gr < M)
            ((uint*)Hh)[(size_t)gr * 64 + cu] = *(const uint*)&hl[rr][cu * 2];
    }
}

// ========================= edge aggregation ==============================
// One wave per dst node. Round-6: edge weights computed IN-KERNEL,
// wave-parallel (phase A): lane e computes w = exp(lrelu(asrc[csr[e]]+ad))
// for edge beg+e and parks {w, src} in per-wave LDS scratch; the chunk loop
// (phase B) then reads records from LDS (broadcast, ~no latency) and runs
// EIGHT row gathers in flight. This deletes the edge_w kernel and its
// 12.8MB/layer global record round-trip (prev round proved the record
// prefetch pipeline was worthless: 69.4us unchanged; the global record
// traffic itself is what we can remove).
// Weight values and accumulation grouping identical -> bit-same output.

#define EW_CAP 128   // per-wave LDS record capacity (deg>128 handled by loop)

template <int FINAL>
__global__ __launch_bounds__(256) void aggregate_k(
    const _Float16* __restrict__ h, const float* __restrict__ asrc,
    const float* __restrict__ adst, const int* __restrict__ off,
    const int* __restrict__ csr, const float* __restrict__ bias,
    float* __restrict__ out_f, __bf16* __restrict__ a_hi, __bf16* __restrict__ a_lo,
    int N, int E) {
    __shared__ int2 srec[4][EW_CAP];
    int gid = blockIdx.x * blockDim.x + threadIdx.x;
    int wid = gid >> 6, lane = gid & 63;
    int wv = (threadIdx.x >> 6);
    if (wid >= N) return;
    const uint* hrows = (const uint*)h;   // 64 uints (128 fp16) per row
    float ad = adst[wid];
    float acc0, acc1, denom;

    {   // self loop (all lanes compute same weight; identical fp ops)
        float e = asrc[wid] + ad;
        e = (e > 0.f) ? e : NEG_SLOPE * e;
        float w = __expf(e);
        float2 f = h2_to_f2(hrows[(size_t)wid * 64 + lane]);
        denom = w; acc0 = w * f.x; acc1 = w * f.y;
    }

    int beg = __builtin_amdgcn_readfirstlane(off[wid]);
    int end = __builtin_amdgcn_readfirstlane(off[wid + 1]);

    for (int sc = beg; sc < end; sc += EW_CAP) {
        int cnt = end - sc; cnt = (cnt < EW_CAP) ? cnt : EW_CAP;

        // ---- phase A: wave-parallel weight compute into LDS ----
        for (int e0 = lane; e0 < cnt; e0 += 64) {
            int s = csr[sc + e0];
            float e = asrc[s] + ad;
            e = (e > 0.f) ? e : NEG_SLOPE * e;
            srec[wv][e0] = make_int2(__float_as_int(__expf(e)), s);
        }
        // same-wave LDS visibility: drain lgkm, fence compiler reordering
        asm volatile("s_waitcnt lgkmcnt(0)" ::: "memory");

        // ---- phase B: chunks of 8, 8 row gathers in flight ----
        int cm1 = cnt - 1;
        for (int j = 0; j < cnt; j += 8) {
            int2 r0 = srec[wv][j];
            int2 r1 = srec[wv][(j + 1 <= cm1) ? j + 1 : cm1];
            int2 r2 = srec[wv][(j + 2 <= cm1) ? j + 2 : cm1];
            int2 r3 = srec[wv][(j + 3 <= cm1) ? j + 3 : cm1];
            int2 r4 = srec[wv][(j + 4 <= cm1) ? j + 4 : cm1];
            int2 r5 = srec[wv][(j + 5 <= cm1) ? j + 5 : cm1];
            int2 r6 = srec[wv][(j + 6 <= cm1) ? j + 6 : cm1];
            int2 r7 = srec[wv][(j + 7 <= cm1) ? j + 7 : cm1];
            int s0 = __builtin_amdgcn_readfirstlane(r0.y);
            int s1 = __builtin_amdgcn_readfirstlane(r1.y);
            int s2 = __builtin_amdgcn_readfirstlane(r2.y);
            int s3 = __builtin_amdgcn_readfirstlane(r3.y);
            int s4 = __builtin_amdgcn_readfirstlane(r4.y);
            int s5 = __builtin_amdgcn_readfirstlane(r5.y);
            int s6 = __builtin_amdgcn_readfirstlane(r6.y);
            int s7 = __builtin_amdgcn_readfirstlane(r7.y);
            uint v0 = hrows[(size_t)s0 * 64 + lane];
            uint v1 = hrows[(size_t)s1 * 64 + lane];
            uint v2 = hrows[(size_t)s2 * 64 + lane];
            uint v3 = hrows[(size_t)s3 * 64 + lane];
            uint v4 = hrows[(size_t)s4 * 64 + lane];
            uint v5 = hrows[(size_t)s5 * 64 + lane];
            uint v6 = hrows[(size_t)s6 * 64 + lane];
            uint v7 = hrows[(size_t)s7 * 64 + lane];

            float w0 = __int_as_float(r0.x);
            float w1 = (j + 1 < cnt) ? __int_as_float(r1.x) : 0.f;
            float w2 = (j + 2 < cnt) ? __int_as_float(r2.x) : 0.f;
            float w3 = (j + 3 < cnt) ? __int_as_float(r3.x) : 0.f;
            float w4 = (j + 4 < cnt) ? __int_as_float(r4.x) : 0.f;
            float w5 = (j + 5 < cnt) ? __int_as_float(r5.x) : 0.f;
            float w6 = (j + 6 < cnt) ? __int_as_float(r6.x) : 0.f;
            float w7 = (j + 7 < cnt) ? __int_as_float(r7.x) : 0.f;

            // grouping identical to the historical chunk-4 iterations
            denom += (w0 + w1) + (w2 + w3);
            float2 f0 = h2_to_f2(v0), f1 = h2_to_f2(v1);
            float2 f2 = h2_to_f2(v2), f3 = h2_to_f2(v3);
            acc0 += w0 * f0.x + w1 * f1.x + w2 * f2.x + w3 * f3.x;
            acc1 += w0 * f0.y + w1 * f1.y + w2 * f2.y + w3 * f3.y;

            denom += (w4 + w5) + (w6 + w7);
            float2 f4 = h2_to_f2(v4), f5 = h2_to_f2(v5);
            float2 f6 = h2_to_f2(v6), f7 = h2_to_f2(v7);
            acc0 += w4 * f4.x + w5 * f5.x + w6 * f6.x + w7 * f7.x;
            acc1 += w4 * f4.y + w5 * f5.y + w6 * f6.y + w7 * f7.y;
        }
        // fence before next superchunk overwrites srec
        asm volatile("s_waitcnt lgkmcnt(0)" ::: "memory");
    }

    float inv = 1.0f / denom;
    float2 b2 = ((const float2*)bias)[lane];
    float o0 = acc0 * inv + b2.x;
    float o1 = acc1 * inv + b2.y;
    if (FINAL) {
        ((float2*)out_f)[(size_t)wid * 64 + lane] = make_float2(o0, o1);
    } else {
        o0 = (o0 > 0.f) ? o0 : (__expf(o0) - 1.0f);   // ELU
        o1 = (o1 > 0.f) ? o1 : (__expf(o1) - 1.0f);
        __bf16 h0 = (__bf16)o0, h1 = (__bf16)o1;
        bf16x2 ph = { h0, h1 };
        bf16x2 pl = { (__bf16)(o0 - (float)h0), (__bf16)(o1 - (float)h1) };
        ((bf16x2*)a_hi)[(size_t)wid * 64 + lane] = ph;
        ((bf16x2*)a_lo)[(size_t)wid * 64 + lane] = pl;
    }
}

// ============================ launch =====================================

extern "C" void kernel_launch(void* const* d_in, const int* in_sizes, int n_in,
                              void* d_out, int out_size, void* d_ws, size_t ws_size,
                              hipStream_t stream) {
    const float* x = (const float*)d_in[0];
    const int* ei = (const int*)d_in[1];
    int N = in_sizes[0] / 128;
    int E = in_sizes[1] / 2;
    const int* src = ei;
    const int* dst = ei + E;

    const float* Wl_[3] = { (const float*)d_in[2], (const float*)d_in[6], (const float*)d_in[10] };
    const float* asl[3] = { (const float*)d_in[3], (const float*)d_in[7], (const float*)d_in[11] };
    const float* adl[3] = { (const float*)d_in[4], (const float*)d_in[8], (const float*)d_in[12] };
    const float* bl[3]  = { (const float*)d_in[5], (const float*)d_in[9], (const float*)d_in[13] };

    // ---- workspace (~34 MB) ----
    size_t nfeat = (size_t)N * 128;
    char* p = (char*)d_ws;
    _Float16* Hh = (_Float16*)p; p += nfeat * 2;       // fp16 gather table
    __bf16* Wfh = (__bf16*)p; p += 3 * 16384 * 2;      // fragment-ordered W hi
    __bf16* Wfl = (__bf16*)p; p += 3 * 16384 * 2;      // fragment-ordered W lo
    float* asrc = (float*)p;  p += (size_t)N * 4;
    float* adst = (float*)p;  p += (size_t)N * 4;
    int* off    = (int*)p;    p += (size_t)(N + 1) * 4;
    int* bsum   = (int*)p;    p += 4096 * 4;
    int* csr    = (int*)p;    p += (size_t)E * 4;

    // Scratch that ALIASES the Hh region (dead until the first gemm, which
    // runs after CSR build): padded deg counters (N*128B = 12.8MB) then the
    // per-edge rank array (6.4MB). 19.2MB <= Hh's 25.6MB.
    int* cpad = (int*)Hh;
    int* rank = (int*)((char*)Hh + ((size_t)N << CPAD) * sizeof(int));

    // activations ping-pong through d_out: hi then lo bf16 (= 51.2 MB total)
    __bf16* A_hi = (__bf16*)d_out;
    __bf16* A_lo = A_hi + nfeat;

    int G = (N + 1023) / 1024;

    // ---- CSR build (grouped by dst) ----
    hipMemsetAsync(cpad, 0, ((size_t)N << CPAD) * sizeof(int), stream);
    count_deg_rank<<<2048, 256, 0, stream>>>(dst, cpad, rank, E);
    scan_block_k<<<G, 256, 0, stream>>>(cpad, off, bsum, N);
    scan_bsum_k<<<1, 1024, 0, stream>>>(bsum, G);
    add_bsum_k<<<(N + 256) / 256, 256, 0, stream>>>(off, bsum, N, E);
    fill_scatter<<<2048, 256, 0, stream>>>(src, dst, rank, off, csr, E);

    // ---- splits ----
    split_w_k<<<dim3(64, 3), 256, 0, stream>>>(Wl_[0], Wl_[1], Wl_[2], Wfh, Wfl);
    int n4 = (int)(nfeat / 4);
    split_x_k<<<(n4 + 255) / 256, 256, 0, stream>>>(x, A_hi, A_lo, n4);

    int gemm_blocks = (N + 63) / 64;
    int wave_blocks = (N + 3) / 4;

    for (int l = 0; l < 3; ++l) {
        gemm_split<<<gemm_blocks, 256, 0, stream>>>(
            A_hi, A_lo, Wfh + (size_t)l * 16384, Wfl + (size_t)l * 16384,
            asl[l], adl[l], Hh, asrc, adst, N);
        if (l < 2) {
            aggregate_k<0><<<wave_blocks, 256, 0, stream>>>(
                Hh, asrc, adst, off, csr, bl[l], nullptr, A_hi, A_lo, N, E);
        } else {
            aggregate_k<1><<<wave_blocks, 256, 0, stream>>>(
                Hh, asrc, adst, off, csr, bl[l], (float*)d_out, nullptr, nullptr, N, E);
        }
    }
}